// Round 7
// baseline (80.779 us; speedup 1.0000x reference)
//
#include <hip/hip_runtime.h>

// Problem constants (fixed by setup_inputs)
#define NB 16
#define NC 64
#define TX 128
#define TY 128
#define DD 768
#define BK 64
#define NT (DD / BK) // 12 K-steps

typedef __bf16 bf16_t;
typedef __bf16 bf16x8 __attribute__((ext_vector_type(8)));
typedef __bf16 bf16x4 __attribute__((ext_vector_type(4)));
typedef float  f32x4  __attribute__((ext_vector_type(4)));

// B LDS tile: 128 rows x 64 bf16 = 128 B/row. XOR swizzle: 16B slot ^= row&7.
// Frag b128 reads (16 lanes, same slot, rows r..r+15) spread across 8 slots
// -> ~2-way, free (m136); writes ~4-way.
__device__ __forceinline__ unsigned swz(unsigned r, unsigned byte) {
  return r * 128u + ((((byte >> 4) & 7u) ^ (r & 7u)) << 4) + (byte & 15u);
}

// fp32x4 -> bf16x4 (packs to v_cvt_pk_bf16_f32), 8B store
__device__ __forceinline__ void cvt_store(void* dst, f32x4 v) {
  bf16x4 q;
  q[0] = (bf16_t)v[0]; q[1] = (bf16_t)v[1]; q[2] = (bf16_t)v[2]; q[3] = (bf16_t)v[3];
  *(bf16x4*)dst = q;
}

// two f32x4 -> one bf16x8 MFMA A-fragment
__device__ __forceinline__ bf16x8 cvt8(f32x4 lo, f32x4 hi) {
  bf16x8 q;
  q[0] = (bf16_t)lo[0]; q[1] = (bf16_t)lo[1]; q[2] = (bf16_t)lo[2]; q[3] = (bf16_t)lo[3];
  q[4] = (bf16_t)hi[0]; q[5] = (bf16_t)hi[1]; q[6] = (bf16_t)hi[2]; q[7] = (bf16_t)hi[3];
  return q;
}

// 8 waves x 64 = 512 threads; each wave owns a 16x128 output strip.
// A (xs) is NOT staged in LDS: zero cross-wave reuse -> direct L2 loads,
// prefetched one iter ahead. B (ys) keeps LDS staging (8-way wave reuse).
__global__ __launch_bounds__(512, 2) void ur_score_kernel(
    const float* __restrict__ xs, const float* __restrict__ ys,
    float* __restrict__ out)
{
  // [buf][128 rows * 128 B] B-only -- 32 KB/block
  __shared__ char lds[2][16384];
  __shared__ float wsum[8];

  // XCD-aware remap: u%16 == b -> all same-b blocks on one XCD;
  // xs[b] (393 KB fp32, 786 KB per XCD) stays L2-resident there.
  const int u  = blockIdx.x;
  const int b  = u & 15;
  const int c  = u >> 4;
  const int bc = b * NC + c;

  const int tid  = threadIdx.x;
  const int lane = tid & 63;
  const int w    = tid >> 6;         // wave 0..7

  // B staging: 2048 float4/tile, 512 threads -> 4 chunks each at
  //   row = r0 + 32*i (i=0..3). (row&7) i-invariant -> LDS off = soff0+4096i.
  const unsigned r0 = (unsigned)tid >> 4;   // 0..31
  const unsigned j0 = (unsigned)tid & 15u;  // 0..15
  const unsigned soff0 = swz(r0, j0 * 8u);
  const float* Bp = ys + (size_t)bc * TY * DD + r0 * DD + j0 * 4;

  // A-direct: lane holds A[arow][t*64 + s*32 + ak .. +8] per substep s
  const unsigned arow = (unsigned)(w * 16 + (lane & 15));
  const unsigned ak   = ((unsigned)(lane >> 4)) << 3;
  const float* Afp = xs + (size_t)b * TX * DD + arow * DD + ak;

  f32x4 acc[8];
  #pragma unroll
  for (int n = 0; n < 8; ++n)
    #pragma unroll
    for (int k = 0; k < 4; ++k)
      acc[n][k] = 0.0f;

  f32x4 pb[4];            // B prefetch (next tile)
  f32x4 afp0, afp1, afp2, afp3;  // A fp32 prefetch: [s*2+half]

  // ---- prologue ----
  afp0 = *(const f32x4*)(Afp + 0);
  afp1 = *(const f32x4*)(Afp + 4);
  afp2 = *(const f32x4*)(Afp + 32);
  afp3 = *(const f32x4*)(Afp + 36);
  #pragma unroll
  for (int i = 0; i < 4; ++i)
    pb[i] = __builtin_nontemporal_load((const f32x4*)(Bp + i * 32 * DD));
  #pragma unroll
  for (int i = 0; i < 4; ++i)
    cvt_store(&lds[0][soff0 + 4096u * i], pb[i]);
  #pragma unroll
  for (int i = 0; i < 4; ++i)
    pb[i] = __builtin_nontemporal_load((const f32x4*)(Bp + BK + i * 32 * DD));
  // barrier WITHOUT vmem drain: only LDS ops must be visible
  asm volatile("s_waitcnt lgkmcnt(0)" ::: "memory");
  __builtin_amdgcn_s_barrier();
  asm volatile("" ::: "memory");

  const unsigned kb = ((unsigned)lane >> 4) << 4;   // 0/16/32/48 B
  const unsigned rB = (unsigned)(lane & 15);        // B frag base row (y)
  const unsigned boff0 = swz(rB, kb), boff1 = swz(rB, 64u + kb); // +16 rows = +2048

  int cur = 0;
  for (int t = 0; t < NT; ++t) {
    // 1) consume A prefetch regs -> bf16 frags (loads got >= 1 full iter)
    bf16x8 af0 = cvt8(afp0, afp1);
    bf16x8 af1 = cvt8(afp2, afp3);
    // 2) re-issue A prefetch for t+1 (covers MFMA+stage phase > L2 latency)
    if (t + 1 < NT) {
      const float* An = Afp + (t + 1) * BK;
      afp0 = *(const f32x4*)(An + 0);
      afp1 = *(const f32x4*)(An + 4);
      afp2 = *(const f32x4*)(An + 32);
      afp3 = *(const f32x4*)(An + 36);
    }
    // 3) B frags + MFMA, two K=32 substeps
    {
      bf16x8 bfr[8];
      #pragma unroll
      for (int n = 0; n < 8; ++n)
        bfr[n] = *(const bf16x8*)&lds[cur][boff0 + 2048u * n];
      #pragma unroll
      for (int n = 0; n < 8; ++n)
        acc[n] = __builtin_amdgcn_mfma_f32_16x16x32_bf16(af0, bfr[n], acc[n], 0, 0, 0);
    }
    {
      bf16x8 bfr[8];
      #pragma unroll
      for (int n = 0; n < 8; ++n)
        bfr[n] = *(const bf16x8*)&lds[cur][boff1 + 2048u * n];
      #pragma unroll
      for (int n = 0; n < 8; ++n)
        acc[n] = __builtin_amdgcn_mfma_f32_16x16x32_bf16(af1, bfr[n], acc[n], 0, 0, 0);
    }
    // 4) convert + write B tile t+1 (its loads got a full iteration in flight)
    if (t + 1 < NT) {
      #pragma unroll
      for (int i = 0; i < 4; ++i)
        cvt_store(&lds[cur ^ 1][soff0 + 4096u * i], pb[i]);
    }
    // 5) issue B tile t+2; stays in flight across the raw barrier
    if (t + 2 < NT) {
      #pragma unroll
      for (int i = 0; i < 4; ++i)
        pb[i] = __builtin_nontemporal_load((const f32x4*)(Bp + (t + 2) * BK + i * 32 * DD));
    }
    // barrier with LDS-only drain (vmem prefetch stays in flight)
    asm volatile("s_waitcnt lgkmcnt(0)" ::: "memory");
    __builtin_amdgcn_s_barrier();
    asm volatile("" ::: "memory");
    cur ^= 1;
  }

  // ---- reduction: max over y, sum over x ----
  // acc element (n,i) at lane l: x = w*16 + (l>>4)*4 + i, y = n*16 + (l&15)
  float rm[4];
  #pragma unroll
  for (int i = 0; i < 4; ++i) {
    float v = acc[0][i];
    #pragma unroll
    for (int n = 1; n < 8; ++n) v = fmaxf(v, acc[n][i]);
    rm[i] = v;
  }
  #pragma unroll
  for (int mask = 1; mask < 16; mask <<= 1)
    #pragma unroll
    for (int i = 0; i < 4; ++i)
      rm[i] = fmaxf(rm[i], __shfl_xor(rm[i], mask, 64));

  float ps = rm[0] + rm[1] + rm[2] + rm[3];
  ps += __shfl_xor(ps, 16, 64);
  ps += __shfl_xor(ps, 32, 64);

  if (lane == 0) wsum[w] = ps;
  __syncthreads();
  if (tid == 0) {
    float s = 0.0f;
    #pragma unroll
    for (int i = 0; i < 8; ++i) s += wsum[i];
    out[bc] = s;
  }
}

extern "C" void kernel_launch(void* const* d_in, const int* in_sizes, int n_in,
                              void* d_out, int out_size, void* d_ws, size_t ws_size,
                              hipStream_t stream) {
  const float* xs = (const float*)d_in[0];
  const float* ys = (const float*)d_in[1];
  float* out = (float*)d_out;
  ur_score_kernel<<<dim3(NB * NC), dim3(512), 0, stream>>>(xs, ys, out);
}

// Round 8
// 75.578 us; speedup vs baseline: 1.0688x; 1.0688x over previous
//
#include <hip/hip_runtime.h>

// Problem constants (fixed by setup_inputs)
#define NB 16
#define NC 64
#define TX 128
#define TY 128
#define DD 768
#define BK 64
#define NT (DD / BK) // 12 K-steps

typedef __bf16 bf16_t;
typedef __bf16 bf16x8 __attribute__((ext_vector_type(8)));
typedef __bf16 bf16x4 __attribute__((ext_vector_type(4)));
typedef float  f32x4  __attribute__((ext_vector_type(4)));

// LDS tile: 128 rows x 64 bf16 = 128 B/row. XOR swizzle: 16B slot ^= row&7.
// Frag b128 reads (16 lanes, same slot, rows r..r+15) spread across 8 slots
// -> ~2-way, free (m136); writes ~4-way.
__device__ __forceinline__ unsigned swz(unsigned r, unsigned byte) {
  return r * 128u + ((((byte >> 4) & 7u) ^ (r & 7u)) << 4) + (byte & 15u);
}

// fp32x4 -> bf16x4 (packs to v_cvt_pk_bf16_f32), 8B store
__device__ __forceinline__ void cvt_store(void* dst, f32x4 v) {
  bf16x4 q;
  q[0] = (bf16_t)v[0]; q[1] = (bf16_t)v[1]; q[2] = (bf16_t)v[2]; q[3] = (bf16_t)v[3];
  *(bf16x4*)dst = q;
}

// 8 waves x 64 = 512 threads; each wave owns a 16x128 output strip.
// 2 blocks/CU (128 KB LDS), 16 waves/CU, <=128 VGPR.
// B prefetch is 2-deep (ping-pong reg sets): the tile written to LDS at
// iter t was loaded at iter t-2, so the iter-top vmcnt wait is pre-paid
// and the HBM stream stays continuously paced across barriers.
__global__ __launch_bounds__(512, 2) void ur_score_kernel(
    const float* __restrict__ xs, const float* __restrict__ ys,
    float* __restrict__ out)
{
  // [buf][A=0/B=1][128 rows * 128 B] -- 64 KB/block
  __shared__ char lds[2][2][16384];
  __shared__ float wsum[8];

  // XCD-aware remap: u%16 == b -> u%8 == b%8, all same-b blocks on one XCD;
  // xs[b] (393 KB fp32) stays L2-resident there.
  const int u  = blockIdx.x;
  const int b  = u & 15;
  const int c  = u >> 4;
  const int bc = b * NC + c;

  const int tid  = threadIdx.x;
  const int lane = tid & 63;
  const int w    = tid >> 6;         // wave 0..7

  // Staging: 2048 float4/tile per operand, 512 threads -> 4 chunks each at
  //   row = r0 + 32*i (i=0..3). (row&7) i-invariant -> LDS off = soff0+4096i.
  const unsigned r0 = (unsigned)tid >> 4;   // 0..31
  const unsigned j0 = (unsigned)tid & 15u;  // 0..15
  const unsigned soff0 = swz(r0, j0 * 8u);
  const float* Ap = xs + (size_t)b  * TX * DD + r0 * DD + j0 * 4;
  const float* Bp = ys + (size_t)bc * TY * DD + r0 * DD + j0 * 4;

  f32x4 acc[8];
  #pragma unroll
  for (int n = 0; n < 8; ++n)
    #pragma unroll
    for (int k = 0; k < 4; ++k)
      acc[n][k] = 0.0f;

  f32x4 pa[4];          // A prefetch, 1-deep (L2-resident)
  f32x4 pbE[4], pbO[4]; // B prefetch, 2-deep ping-pong

  // ---- prologue: tile0 -> regs -> lds[0]; A(1),B(1),B(2) -> regs ----
  #pragma unroll
  for (int i = 0; i < 4; ++i) {
    pa[i]  = *(const f32x4*)(Ap + i * 32 * DD);
    pbE[i] = __builtin_nontemporal_load((const f32x4*)(Bp + i * 32 * DD));
  }
  #pragma unroll
  for (int i = 0; i < 4; ++i) {
    cvt_store(&lds[0][0][soff0 + 4096u * i], pa[i]);
    cvt_store(&lds[0][1][soff0 + 4096u * i], pbE[i]);
  }
  #pragma unroll
  for (int i = 0; i < 4; ++i)
    pa[i]  = *(const f32x4*)(Ap + BK + i * 32 * DD);
  #pragma unroll
  for (int i = 0; i < 4; ++i)
    pbE[i] = __builtin_nontemporal_load((const f32x4*)(Bp + BK + i * 32 * DD));
  #pragma unroll
  for (int i = 0; i < 4; ++i)
    pbO[i] = __builtin_nontemporal_load((const f32x4*)(Bp + 2 * BK + i * 32 * DD));
  // barrier WITHOUT vmem drain: only LDS ops must be visible
  asm volatile("s_waitcnt lgkmcnt(0)" ::: "memory");
  __builtin_amdgcn_s_barrier();
  asm volatile("" ::: "memory");

  const unsigned kb = ((unsigned)lane >> 4) << 4;          // 0/16/32/48 B
  const unsigned rA = (unsigned)(w * 16 + (lane & 15));    // A row this wave
  const unsigned rB = (unsigned)(lane & 15);               // B rows (y)
  const unsigned aoff0 = swz(rA, kb), aoff1 = swz(rA, 64u + kb);
  const unsigned boff0 = swz(rB, kb), boff1 = swz(rB, 64u + kb); // +16 rows=+2048

  // Per iter T (buffer CUR = T&1, PB = E if T even else O):
  //  1) cvt_store A(T+1) from pa, B(T+1) from PB  [B loaded 2 iters ago]
  //  2) issue A(T+2) -> pa, B(T+3) -> PB          [2-iter flight time]
  //  3) MFMA on lds[CUR], two K=32 substeps
  //  4) lgkm-only barrier (vmem prefetch stays in flight)
  #define ITER(T, CUR, PB)                                                        \
  {                                                                               \
    if ((T) + 1 < NT) {                                                           \
      _Pragma("unroll")                                                           \
      for (int i = 0; i < 4; ++i) {                                               \
        cvt_store(&lds[(CUR) ^ 1][0][soff0 + 4096u * i], pa[i]);                  \
        cvt_store(&lds[(CUR) ^ 1][1][soff0 + 4096u * i], PB[i]);                  \
      }                                                                           \
    }                                                                             \
    if ((T) + 2 < NT) {                                                           \
      _Pragma("unroll")                                                           \
      for (int i = 0; i < 4; ++i)                                                 \
        pa[i] = *(const f32x4*)(Ap + ((T) + 2) * BK + i * 32 * DD);               \
    }                                                                             \
    if ((T) + 3 < NT) {                                                           \
      _Pragma("unroll")                                                           \
      for (int i = 0; i < 4; ++i)                                                 \
        PB[i] = __builtin_nontemporal_load(                                       \
            (const f32x4*)(Bp + ((T) + 3) * BK + i * 32 * DD));                   \
    }                                                                             \
    {                                                                             \
      bf16x8 af0 = *(const bf16x8*)&lds[CUR][0][aoff0];                           \
      bf16x8 bfr[8];                                                              \
      _Pragma("unroll")                                                           \
      for (int n = 0; n < 8; ++n)                                                 \
        bfr[n] = *(const bf16x8*)&lds[CUR][1][boff0 + 2048u * n];                 \
      _Pragma("unroll")                                                           \
      for (int n = 0; n < 8; ++n)                                                 \
        acc[n] = __builtin_amdgcn_mfma_f32_16x16x32_bf16(af0, bfr[n], acc[n], 0, 0, 0); \
    }                                                                             \
    {                                                                             \
      bf16x8 af1 = *(const bf16x8*)&lds[CUR][0][aoff1];                           \
      bf16x8 bfr[8];                                                              \
      _Pragma("unroll")                                                           \
      for (int n = 0; n < 8; ++n)                                                 \
        bfr[n] = *(const bf16x8*)&lds[CUR][1][boff1 + 2048u * n];                 \
      _Pragma("unroll")                                                           \
      for (int n = 0; n < 8; ++n)                                                 \
        acc[n] = __builtin_amdgcn_mfma_f32_16x16x32_bf16(af1, bfr[n], acc[n], 0, 0, 0); \
    }                                                                             \
    asm volatile("s_waitcnt lgkmcnt(0)" ::: "memory");                            \
    __builtin_amdgcn_s_barrier();                                                 \
    asm volatile("" ::: "memory");                                                \
  }

  #pragma unroll 1
  for (int tt = 0; tt < NT; tt += 2) {
    ITER(tt,     0, pbE);
    ITER(tt + 1, 1, pbO);
  }
  #undef ITER

  // ---- reduction: max over y, sum over x ----
  // acc element (n,i) at lane l: x = w*16 + (l>>4)*4 + i, y = n*16 + (l&15)
  float rm[4];
  #pragma unroll
  for (int i = 0; i < 4; ++i) {
    float v = acc[0][i];
    #pragma unroll
    for (int n = 1; n < 8; ++n) v = fmaxf(v, acc[n][i]);
    rm[i] = v;
  }
  // max across the 16 lanes holding different y for the same x-set
  #pragma unroll
  for (int mask = 1; mask < 16; mask <<= 1)
    #pragma unroll
    for (int i = 0; i < 4; ++i)
      rm[i] = fmaxf(rm[i], __shfl_xor(rm[i], mask, 64));

  // per-lane sum over its 4 distinct x rows, then combine the 4 lane-groups
  float ps = rm[0] + rm[1] + rm[2] + rm[3];
  ps += __shfl_xor(ps, 16, 64);
  ps += __shfl_xor(ps, 32, 64);

  if (lane == 0) wsum[w] = ps;
  __syncthreads();
  if (tid == 0) {
    float s = 0.0f;
    #pragma unroll
    for (int i = 0; i < 8; ++i) s += wsum[i];
    out[bc] = s;
  }
}

extern "C" void kernel_launch(void* const* d_in, const int* in_sizes, int n_in,
                              void* d_out, int out_size, void* d_ws, size_t ws_size,
                              hipStream_t stream) {
  const float* xs = (const float*)d_in[0];
  const float* ys = (const float*)d_in[1];
  float* out = (float*)d_out;
  ur_score_kernel<<<dim3(NB * NC), dim3(512), 0, stream>>>(xs, ys, out);
}

// Round 9
// 75.094 us; speedup vs baseline: 1.0757x; 1.0064x over previous
//
#include <hip/hip_runtime.h>

// Problem constants (fixed by setup_inputs)
#define NB 16
#define NC 64
#define TX 128
#define TY 128
#define DD 768
#define BK 64
#define NT (DD / BK) // 12 K-steps

typedef __bf16 bf16_t;
typedef __bf16 bf16x8 __attribute__((ext_vector_type(8)));
typedef __bf16 bf16x4 __attribute__((ext_vector_type(4)));
typedef float  f32x4  __attribute__((ext_vector_type(4)));

// LDS tile: 128 rows x 64 bf16 = 128 B/row. XOR swizzle: 16B slot ^= row&7.
// Frag b128 reads (16 lanes, same slot, rows r..r+15) spread across 8 slots
// -> ~2-way, free (m136); writes ~4-way.
__device__ __forceinline__ unsigned swz(unsigned r, unsigned byte) {
  return r * 128u + ((((byte >> 4) & 7u) ^ (r & 7u)) << 4) + (byte & 15u);
}

// fp32x4 -> bf16x4 (packs to v_cvt_pk_bf16_f32), 8B store
__device__ __forceinline__ void cvt_store(void* dst, f32x4 v) {
  bf16x4 q;
  q[0] = (bf16_t)v[0]; q[1] = (bf16_t)v[1]; q[2] = (bf16_t)v[2]; q[3] = (bf16_t)v[3];
  *(bf16x4*)dst = q;
}

// 8 waves x 64 = 512 threads; each wave owns a 16x128 output strip.
// 2 blocks/CU (128 KB LDS), 16 waves/CU, <=128 VGPR.
// B prefetch: PAIRED-COLUMN bursts. On even iters, issue B(t+2) AND B(t+3)
// back-to-back: the two 256B row-chunks are column-adjacent (512B span,
// mostly same DRAM page) -> page hit instead of a fresh activation,
// cutting the ys activation rate ~1.7x (K-sliced streaming re-opens each
// 3KB row's pages every iteration otherwise).
__global__ __launch_bounds__(512, 2) void ur_score_kernel(
    const float* __restrict__ xs, const float* __restrict__ ys,
    float* __restrict__ out)
{
  // [buf][A=0/B=1][128 rows * 128 B] -- 64 KB/block
  __shared__ char lds[2][2][16384];
  __shared__ float wsum[8];

  // XCD-aware remap: u%16 == b -> u%8 == b%8, all same-b blocks on one XCD;
  // xs[b] (393 KB fp32) stays L2-resident there.
  const int u  = blockIdx.x;
  const int b  = u & 15;
  const int c  = u >> 4;
  const int bc = b * NC + c;

  const int tid  = threadIdx.x;
  const int lane = tid & 63;
  const int w    = tid >> 6;         // wave 0..7

  // Staging: 2048 float4/tile per operand, 512 threads -> 4 chunks each at
  //   row = r0 + 32*i (i=0..3). (row&7) i-invariant -> LDS off = soff0+4096i.
  const unsigned r0 = (unsigned)tid >> 4;   // 0..31
  const unsigned j0 = (unsigned)tid & 15u;  // 0..15
  const unsigned soff0 = swz(r0, j0 * 8u);
  const float* Ap = xs + (size_t)b  * TX * DD + r0 * DD + j0 * 4;
  const float* Bp = ys + (size_t)bc * TY * DD + r0 * DD + j0 * 4;

  f32x4 acc[8];
  #pragma unroll
  for (int n = 0; n < 8; ++n)
    #pragma unroll
    for (int k = 0; k < 4; ++k)
      acc[n][k] = 0.0f;

  f32x4 pa[4];          // A prefetch, 1-deep (L2-resident)
  f32x4 pbE[4], pbO[4]; // B prefetch, paired-column burst sets

  // ---- prologue: A(0),B(0),B(1) -> regs; A(0),B(0) -> lds[0]; A(1) -> regs
  #pragma unroll
  for (int i = 0; i < 4; ++i)
    pa[i]  = *(const f32x4*)(Ap + i * 32 * DD);
  #pragma unroll
  for (int i = 0; i < 4; ++i) {   // paired burst: cols 0..511 B, same pages
    pbE[i] = __builtin_nontemporal_load((const f32x4*)(Bp + i * 32 * DD));
    pbO[i] = __builtin_nontemporal_load((const f32x4*)(Bp + BK + i * 32 * DD));
  }
  #pragma unroll
  for (int i = 0; i < 4; ++i) {
    cvt_store(&lds[0][0][soff0 + 4096u * i], pa[i]);
    cvt_store(&lds[0][1][soff0 + 4096u * i], pbE[i]);
  }
  #pragma unroll
  for (int i = 0; i < 4; ++i)
    pa[i]  = *(const f32x4*)(Ap + BK + i * 32 * DD);
  // barrier WITHOUT vmem drain: only LDS ops must be visible
  asm volatile("s_waitcnt lgkmcnt(0)" ::: "memory");
  __builtin_amdgcn_s_barrier();
  asm volatile("" ::: "memory");

  const unsigned kb = ((unsigned)lane >> 4) << 4;          // 0/16/32/48 B
  const unsigned rA = (unsigned)(w * 16 + (lane & 15));    // A row this wave
  const unsigned rB = (unsigned)(lane & 15);               // B rows (y)
  const unsigned aoff0 = swz(rA, kb), aoff1 = swz(rA, 64u + kb);
  const unsigned boff0 = swz(rB, kb), boff1 = swz(rB, 64u + kb); // +16 rows=+2048

  // Even iter T: store A(T+1),B(T+1)=pbO; issue A(T+2); burst pbE=B(T+2),
  //              pbO=B(T+3) back-to-back (column-adjacent -> page hits).
  // Odd  iter T: store A(T+1),B(T+1)=pbE; issue A(T+2); no B issue.
  // MFMA on lds[CUR]; lgkm-only barrier (vmem prefetch stays in flight).
  #define ITER(T, CUR, PBUSE, DOBURST)                                            \
  {                                                                               \
    if ((T) + 1 < NT) {                                                           \
      _Pragma("unroll")                                                           \
      for (int i = 0; i < 4; ++i) {                                               \
        cvt_store(&lds[(CUR) ^ 1][0][soff0 + 4096u * i], pa[i]);                  \
        cvt_store(&lds[(CUR) ^ 1][1][soff0 + 4096u * i], PBUSE[i]);               \
      }                                                                           \
    }                                                                             \
    if ((T) + 2 < NT) {                                                           \
      _Pragma("unroll")                                                           \
      for (int i = 0; i < 4; ++i)                                                 \
        pa[i] = *(const f32x4*)(Ap + ((T) + 2) * BK + i * 32 * DD);               \
    }                                                                             \
    if (DOBURST) {                                                                \
      if ((T) + 3 < NT) {                                                         \
        _Pragma("unroll")                                                         \
        for (int i = 0; i < 4; ++i) {                                             \
          pbE[i] = __builtin_nontemporal_load(                                    \
              (const f32x4*)(Bp + ((T) + 2) * BK + i * 32 * DD));                 \
          pbO[i] = __builtin_nontemporal_load(                                    \
              (const f32x4*)(Bp + ((T) + 3) * BK + i * 32 * DD));                 \
        }                                                                         \
      } else if ((T) + 2 < NT) {                                                  \
        _Pragma("unroll")                                                         \
        for (int i = 0; i < 4; ++i)                                               \
          pbE[i] = __builtin_nontemporal_load(                                    \
              (const f32x4*)(Bp + ((T) + 2) * BK + i * 32 * DD));                 \
      }                                                                           \
    }                                                                             \
    {                                                                             \
      bf16x8 af0 = *(const bf16x8*)&lds[CUR][0][aoff0];                           \
      bf16x8 bfr[8];                                                              \
      _Pragma("unroll")                                                           \
      for (int n = 0; n < 8; ++n)                                                 \
        bfr[n] = *(const bf16x8*)&lds[CUR][1][boff0 + 2048u * n];                 \
      _Pragma("unroll")                                                           \
      for (int n = 0; n < 8; ++n)                                                 \
        acc[n] = __builtin_amdgcn_mfma_f32_16x16x32_bf16(af0, bfr[n], acc[n], 0, 0, 0); \
    }                                                                             \
    {                                                                             \
      bf16x8 af1 = *(const bf16x8*)&lds[CUR][0][aoff1];                           \
      bf16x8 bfr[8];                                                              \
      _Pragma("unroll")                                                           \
      for (int n = 0; n < 8; ++n)                                                 \
        bfr[n] = *(const bf16x8*)&lds[CUR][1][boff1 + 2048u * n];                 \
      _Pragma("unroll")                                                           \
      for (int n = 0; n < 8; ++n)                                                 \
        acc[n] = __builtin_amdgcn_mfma_f32_16x16x32_bf16(af1, bfr[n], acc[n], 0, 0, 0); \
    }                                                                             \
    asm volatile("s_waitcnt lgkmcnt(0)" ::: "memory");                            \
    __builtin_amdgcn_s_barrier();                                                 \
    asm volatile("" ::: "memory");                                                \
  }

  #pragma unroll 1
  for (int tt = 0; tt < NT; tt += 2) {
    ITER(tt,     0, pbO, 1);   // even: store pbO, burst-load pbE+pbO
    ITER(tt + 1, 1, pbE, 0);   // odd:  store pbE, no B issue
  }
  #undef ITER

  // ---- reduction: max over y, sum over x ----
  // acc element (n,i) at lane l: x = w*16 + (l>>4)*4 + i, y = n*16 + (l&15)
  float rm[4];
  #pragma unroll
  for (int i = 0; i < 4; ++i) {
    float v = acc[0][i];
    #pragma unroll
    for (int n = 1; n < 8; ++n) v = fmaxf(v, acc[n][i]);
    rm[i] = v;
  }
  // max across the 16 lanes holding different y for the same x-set
  #pragma unroll
  for (int mask = 1; mask < 16; mask <<= 1)
    #pragma unroll
    for (int i = 0; i < 4; ++i)
      rm[i] = fmaxf(rm[i], __shfl_xor(rm[i], mask, 64));

  // per-lane sum over its 4 distinct x rows, then combine the 4 lane-groups
  float ps = rm[0] + rm[1] + rm[2] + rm[3];
  ps += __shfl_xor(ps, 16, 64);
  ps += __shfl_xor(ps, 32, 64);

  if (lane == 0) wsum[w] = ps;
  __syncthreads();
  if (tid == 0) {
    float s = 0.0f;
    #pragma unroll
    for (int i = 0; i < 8; ++i) s += wsum[i];
    out[bc] = s;
  }
}

extern "C" void kernel_launch(void* const* d_in, const int* in_sizes, int n_in,
                              void* d_out, int out_size, void* d_ws, size_t ws_size,
                              hipStream_t stream) {
  const float* xs = (const float*)d_in[0];
  const float* ys = (const float*)d_in[1];
  float* out = (float*)d_out;
  ur_score_kernel<<<dim3(NB * NC), dim3(512), 0, stream>>>(xs, ys, out);
}